// Round 1
// baseline (872.591 us; speedup 1.0000x reference)
//
#include <hip/hip_runtime.h>
#include <cstdint>
#include <cstddef>

// Problem constants
#define B_   2
#define P_   8192
#define NN_  24
#define C1_  32
#define C2_  32
#define K_   13
#define A_   12
#define DR_  384   // C2_*A_  (rows: d*12+r)
#define CA_  384   // C1_*A_  (cols: c*12+a)
#define PT_  32    // p-tile per block
#define APAD 40    // 32-ca chunk + 8 pad (bank-conflict break: 80B rows)
#define BPAD 392   // 384 + 8 pad (784B rows)

typedef __attribute__((ext_vector_type(8))) short short8;
typedef __attribute__((ext_vector_type(4))) float floatx4;

__device__ __forceinline__ unsigned short f2bf(float f) {
    union { float f; unsigned int u; } v; v.f = f;
    unsigned int u = v.u;
    return (unsigned short)((u + 0x7fffu + ((u >> 16) & 1u)) >> 16); // RNE
}

// ---------------- prep kernels ----------------

// WTg[k][chunk][dr][cc<40] = bf16( W[d,c,m] * k_pos_w[d,m] ),
//   m = idx_map[ tivr[r,k]*12 + tir[r,a] ],  dr=d*12+r, ca=chunk*32+cc=c*12+a.
// Layout is the exact LDS image (rows padded to 40) so staging is a flat copy.
__global__ void build_wt(const float* __restrict__ W, const float* __restrict__ kpw,
                         const int* __restrict__ idx_map, const int* __restrict__ tivr,
                         const int* __restrict__ tir, unsigned short* __restrict__ WTg) {
    int id = blockIdx.x * 256 + threadIdx.x;
    const int TOT = K_ * 12 * DR_ * APAD;
    if (id >= TOT) return;
    int cc = id % APAD;
    int t1 = id / APAD;
    int dr = t1 % DR_;
    int t2 = t1 / DR_;
    int ch = t2 % 12;
    int k  = t2 / 12;
    float val = 0.f;
    if (cc < 32) {
        int ca = ch * 32 + cc;
        int d = dr / 12, r = dr % 12;
        int c = ca / 12, a = ca % 12;
        int kk = tivr[r * K_ + k];
        int ia = tir[r * A_ + a];
        int m  = idx_map[kk * A_ + ia];
        val = W[(d * C1_ + c) * 36 + m] * kpw[d * 36 + m];
    }
    WTg[id] = f2bf(val);
}

__global__ void build_md(const int* __restrict__ nbr, const float* __restrict__ verts,
                         float* __restrict__ md) {
    int t = blockIdx.x * 256 + threadIdx.x;
    if (t >= B_ * P_) return;
    const float* vp = verts + (size_t)t * 3;
    float vx = vp[0], vy = vp[1], vz = vp[2];
    int b = t / P_;
    const int* np = nbr + (size_t)t * NN_;
    float ax = 0.f, ay = 0.f, az = 0.f;
    for (int n = 0; n < NN_; n++) {
        int j = np[n];
        const float* vq = verts + ((size_t)b * P_ + j) * 3;
        float dx = vq[0] - vx, dy = vq[1] - vy, dz = vq[2] - vz;
        float nn = sqrtf(dx * dx + dy * dy + dz * dz);
        float inv = 1.f / fmaxf(nn, 1e-12f);
        ax += dx * inv; ay += dy * inv; az += dz * inv;
    }
    const float s = 1.f / 24.f;
    md[t * 3 + 0] = ax * s; md[t * 3 + 1] = ay * s; md[t * 3 + 2] = az * s;
}

__global__ void build_kpo(const float* __restrict__ kpw, const int* __restrict__ idx_map,
                          const float* __restrict__ vs, float* __restrict__ kpo) {
    int t = blockIdx.x * 64 + threadIdx.x;
    if (t >= C2_ * K_) return;
    int d = t / K_, k = t % K_;
    float x = 0.f, y = 0.f, z = 0.f;
    for (int a = 0; a < A_; a++) {
        float w = kpw[d * 36 + idx_map[k * A_ + a]];
        x += w * vs[a * 3 + 0]; y += w * vs[a * 3 + 1]; z += w * vs[a * 3 + 2];
    }
    float nn = sqrtf(x * x + y * y + z * z);
    float inv = 1.f / fmaxf(nn, 1e-12f);
    kpo[t * 3 + 0] = x * inv; kpo[t * 3 + 1] = y * inv; kpo[t * 3 + 2] = z * inv;
}

__global__ void build_be(const float* __restrict__ bias, const int* __restrict__ lvl,
                         const int* __restrict__ tivr, float* __restrict__ be) {
    int t = blockIdx.x * 64 + threadIdx.x;
    if (t >= DR_) return;
    int d = t / 12, r = t % 12;
    float s = 0.f;
    for (int k = 0; k < K_; k++) s += bias[d * 5 + lvl[tivr[r * K_ + k]]];
    be[t] = s;
}

// ---------------- main fused kernel ----------------
// grid = B_ * (P_/PT_) = 512 blocks, 256 threads (4 waves).
// Block: all 384 dr x 32 p. Wave w: dr in [w*96, w*96+96), 6 m-tiles x 2 n-tiles.
// per k: stage fm slice -> Bs (bf16), compute pw tile; 12 A-chunks of 32 ca with
// 16x16x32 bf16 MFMA into acc_k; epilogue acc_o += pw * acc_k.
__global__ __launch_bounds__(256, 2) void main_gemm(
    const float* __restrict__ fm, const unsigned short* __restrict__ WTg,
    const float* __restrict__ md, const float* __restrict__ kpo,
    const float* __restrict__ be, float* __restrict__ out) {

    __shared__ __attribute__((aligned(16))) unsigned short Bs[PT_][BPAD];  // 25088 B
    __shared__ __attribute__((aligned(16))) unsigned short As[DR_ * APAD]; // 30720 B
    __shared__ float pwS[C2_][PT_];        // 4096 B
    __shared__ float mdS[PT_][3];          // 384 B
    __shared__ float kpoS[C2_ * K_ * 3];   // 4992 B
    __shared__ float biasS[DR_];           // 1536 B

    const int tid  = threadIdx.x;
    const int bid  = blockIdx.x;
    const int b    = bid >> 8;          // bid / 256
    const int p0   = (bid & 255) << 5;  // p-tile base
    const int lane = tid & 63;
    const int wid  = tid >> 6;
    const int rowm = lane & 15;
    const int quad = lane >> 4;

    // small tables
    for (int i = tid; i < PT_ * 3; i += 256) {
        int p = i / 3, c = i % 3;
        mdS[p][c] = md[((size_t)b * P_ + p0 + p) * 3 + c];
    }
    for (int i = tid; i < C2_ * K_ * 3; i += 256) kpoS[i] = kpo[i];
    for (int i = tid; i < DR_; i += 256) biasS[i] = be[i];

    floatx4 acc_o[6][2];
    floatx4 acc_k[6][2];
    #pragma unroll
    for (int mt = 0; mt < 6; mt++)
        #pragma unroll
        for (int nt = 0; nt < 2; nt++) { acc_o[mt][nt] = (floatx4)0.f; acc_k[mt][nt] = (floatx4)0.f; }

    __syncthreads();

    for (int k = 0; k < K_; k++) {
        // ---- stage fm slice -> Bs[p][c*12+a] as bf16 (96 float4 per c, never spans p) ----
        for (int i = tid; i < C1_ * 96; i += 256) {
            int c = i / 96;
            int j = i - c * 96;
            const float4* src = (const float4*)(fm + ((((size_t)b * C1_ + c) * K_ + k) * P_ + p0) * A_) + j;
            float4 v = *src;
            int pl = j / 3;
            int aseg = (j - pl * 3) * 4;
            ushort4 pk = make_ushort4(f2bf(v.x), f2bf(v.y), f2bf(v.z), f2bf(v.w));
            *(ushort4*)&Bs[pl][c * A_ + aseg] = pk;
        }
        // ---- pw tile for this k: relu(mean_dir . k_pos_ori) ----
        for (int i = tid; i < C2_ * PT_; i += 256) {
            int d = i >> 5, pl = i & 31;
            const float* kv = &kpoS[(d * K_ + k) * 3];
            float s = mdS[pl][0] * kv[0] + mdS[pl][1] * kv[1] + mdS[pl][2] * kv[2];
            pwS[d][pl] = fmaxf(s, 0.f);
        }

        // ---- 12 chunks of 32 ca ----
        for (int ch = 0; ch < 12; ch++) {
            { // flat copy of the pre-laid-out A chunk (384x40 ushorts = 1920 uint4)
                const uint4* src = (const uint4*)(WTg + (size_t)(k * 12 + ch) * (DR_ * APAD));
                uint4* dst = (uint4*)As;
                for (int i = tid; i < 1920; i += 256) dst[i] = src[i];
            }
            __syncthreads();  // A staged; (ch==0) also publishes Bs/pwS

            short8 afr[6], bfr[2];
            const unsigned short* abase = As + (wid * 96 + rowm) * APAD + quad * 8;
            #pragma unroll
            for (int mt = 0; mt < 6; mt++) afr[mt] = *(const short8*)(abase + mt * 16 * APAD);
            #pragma unroll
            for (int nt = 0; nt < 2; nt++) bfr[nt] = *(const short8*)(&Bs[nt * 16 + rowm][ch * 32 + quad * 8]);
            #pragma unroll
            for (int mt = 0; mt < 6; mt++)
                #pragma unroll
                for (int nt = 0; nt < 2; nt++)
                    acc_k[mt][nt] = __builtin_amdgcn_mfma_f32_16x16x32_bf16(afr[mt], bfr[nt], acc_k[mt][nt], 0, 0, 0);
            __syncthreads();  // protect As overwrite / Bs re-stage
        }

        // ---- epilogue-k: acc_o += pw[d,p] * acc_k ----
        #pragma unroll
        for (int mt = 0; mt < 6; mt++) {
            int drb = wid * 96 + mt * 16 + quad * 4;
            #pragma unroll
            for (int reg = 0; reg < 4; reg++) {
                int d = (drb + reg) / 12;
                #pragma unroll
                for (int nt = 0; nt < 2; nt++) {
                    float pv = pwS[d][nt * 16 + rowm];
                    acc_o[mt][nt][reg] += pv * acc_k[mt][nt][reg];
                    acc_k[mt][nt][reg] = 0.f;
                }
            }
        }
        __syncthreads();  // protect pwS/Bs for next k
    }

    // ---- final: relu(acc_o + bias_eff), scatter to out[b,d,p,r] ----
    #pragma unroll
    for (int mt = 0; mt < 6; mt++) {
        #pragma unroll
        for (int reg = 0; reg < 4; reg++) {
            int dr = wid * 96 + mt * 16 + quad * 4 + reg;
            int d = dr / 12, r = dr - d * 12;
            #pragma unroll
            for (int nt = 0; nt < 2; nt++) {
                int p = p0 + nt * 16 + rowm;
                float v = acc_o[mt][nt][reg] + biasS[dr];
                v = fmaxf(v, 0.f);
                out[(((size_t)b * C2_ + d) * P_ + p) * A_ + r] = v;
            }
        }
    }
}

// ---------------- launcher ----------------
extern "C" void kernel_launch(void* const* d_in, const int* in_sizes, int n_in,
                              void* d_out, int out_size, void* d_ws, size_t ws_size,
                              hipStream_t stream) {
    const int*   nbr     = (const int*)d_in[0];
    const float* verts   = (const float*)d_in[1];
    const float* fm      = (const float*)d_in[2];
    const float* W       = (const float*)d_in[3];
    const float* bias    = (const float*)d_in[4];
    const float* kpw     = (const float*)d_in[5];
    const float* vs      = (const float*)d_in[6];
    const int*   idx_map = (const int*)d_in[7];
    const int*   tivr    = (const int*)d_in[8];
    const int*   tir     = (const int*)d_in[9];
    const int*   lvl     = (const int*)d_in[10];
    float* out = (float*)d_out;

    char* ws = (char*)d_ws;
    unsigned short* WTg = (unsigned short*)ws;            // 13*12*384*40*2 = 4,792,320 B
    float* md_ws  = (float*)(ws + 4800000);               // 196,608 B
    float* kpo_ws = (float*)(ws + 5000000);               // 4,992 B
    float* be_ws  = (float*)(ws + 5006000);               // 1,536 B

    {
        const int TOT = K_ * 12 * DR_ * APAD;             // 2,396,160
        build_wt<<<TOT / 256, 256, 0, stream>>>(W, kpw, idx_map, tivr, tir, WTg);
    }
    build_md<<<(B_ * P_) / 256, 256, 0, stream>>>(nbr, verts, md_ws);
    build_kpo<<<7, 64, 0, stream>>>(kpw, idx_map, vs, kpo_ws);
    build_be<<<6, 64, 0, stream>>>(bias, lvl, tivr, be_ws);

    main_gemm<<<B_ * (P_ / PT_), 256, 0, stream>>>(fm, WTg, md_ws, kpo_ws, be_ws, out);
}

// Round 2
// 734.474 us; speedup vs baseline: 1.1880x; 1.1880x over previous
//
#include <hip/hip_runtime.h>
#include <cstdint>
#include <cstddef>

// Problem constants
#define B_   2
#define P_   8192
#define NN_  24
#define C1_  32
#define C2_  32
#define K_   13
#define A_   12
#define DR_  384   // C2_*A_  (rows: d*12+r)
#define CA_  384   // C1_*A_  (cols: c*12+a)
#define PT_  32    // p-tile per block
#define BPAD 408   // 384 + 24 pad: stride 204 dwords ≡ 12 (mod 32) -> 2-way (free) b128 reads

typedef __attribute__((ext_vector_type(8))) short short8;
typedef __attribute__((ext_vector_type(4))) float floatx4;

__device__ __forceinline__ unsigned short f2bf(float f) {
    union { float f; unsigned int u; } v; v.f = f;
    unsigned int u = v.u;
    return (unsigned short)((u + 0x7fffu + ((u >> 16) & 1u)) >> 16); // RNE
}

// ---------------- prep kernels ----------------

// WT2[k][dr][ca] = bf16( W[d,c,m] * k_pos_w[d,m] ), unpadded row-major (768 B rows).
// m = idx_map[ tivr[r,k]*12 + tir[r,a] ], dr=d*12+r, ca=c*12+a.
__global__ void build_wt(const float* __restrict__ W, const float* __restrict__ kpw,
                         const int* __restrict__ idx_map, const int* __restrict__ tivr,
                         const int* __restrict__ tir, unsigned short* __restrict__ WT2) {
    int id = blockIdx.x * 256 + threadIdx.x;
    const int TOT = K_ * DR_ * CA_;
    if (id >= TOT) return;
    int ca = id % CA_;
    int t1 = id / CA_;
    int dr = t1 % DR_;
    int k  = t1 / DR_;
    int d = dr / 12, r = dr % 12;
    int c = ca / 12, a = ca % 12;
    int kk = tivr[r * K_ + k];
    int ia = tir[r * A_ + a];
    int m  = idx_map[kk * A_ + ia];
    WT2[id] = f2bf(W[(d * C1_ + c) * 36 + m] * kpw[d * 36 + m]);
}

__global__ void build_md(const int* __restrict__ nbr, const float* __restrict__ verts,
                         float* __restrict__ md) {
    int t = blockIdx.x * 256 + threadIdx.x;
    if (t >= B_ * P_) return;
    const float* vp = verts + (size_t)t * 3;
    float vx = vp[0], vy = vp[1], vz = vp[2];
    int b = t / P_;
    const int* np = nbr + (size_t)t * NN_;
    float ax = 0.f, ay = 0.f, az = 0.f;
    for (int n = 0; n < NN_; n++) {
        int j = np[n];
        const float* vq = verts + ((size_t)b * P_ + j) * 3;
        float dx = vq[0] - vx, dy = vq[1] - vy, dz = vq[2] - vz;
        float nn = sqrtf(dx * dx + dy * dy + dz * dz);
        float inv = 1.f / fmaxf(nn, 1e-12f);
        ax += dx * inv; ay += dy * inv; az += dz * inv;
    }
    const float s = 1.f / 24.f;
    md[t * 3 + 0] = ax * s; md[t * 3 + 1] = ay * s; md[t * 3 + 2] = az * s;
}

__global__ void build_kpo(const float* __restrict__ kpw, const int* __restrict__ idx_map,
                          const float* __restrict__ vs, float* __restrict__ kpo) {
    int t = blockIdx.x * 64 + threadIdx.x;
    if (t >= C2_ * K_) return;
    int d = t / K_, k = t % K_;
    float x = 0.f, y = 0.f, z = 0.f;
    for (int a = 0; a < A_; a++) {
        float w = kpw[d * 36 + idx_map[k * A_ + a]];
        x += w * vs[a * 3 + 0]; y += w * vs[a * 3 + 1]; z += w * vs[a * 3 + 2];
    }
    float nn = sqrtf(x * x + y * y + z * z);
    float inv = 1.f / fmaxf(nn, 1e-12f);
    kpo[t * 3 + 0] = x * inv; kpo[t * 3 + 1] = y * inv; kpo[t * 3 + 2] = z * inv;
}

__global__ void build_be(const float* __restrict__ bias, const int* __restrict__ lvl,
                         const int* __restrict__ tivr, float* __restrict__ be) {
    int t = blockIdx.x * 64 + threadIdx.x;
    if (t >= DR_) return;
    int d = t / 12, r = t % 12;
    float s = 0.f;
    for (int k = 0; k < K_; k++) s += bias[d * 5 + lvl[tivr[r * K_ + k]]];
    be[t] = s;
}

// ---------------- main fused kernel ----------------
// grid = 512 blocks (b x 256 p-tiles of 32), 256 threads (4 waves), 2 blocks/CU.
// Per k: ONE barrier. fm slice double-buffered (register prefetch -> bf16 LDS),
// WT fragments loaded straight from global (L2-hot) double-buffered in regs.
__global__ __launch_bounds__(256, 2) void main_gemm(
    const float* __restrict__ fm, const unsigned short* __restrict__ WT,
    const float* __restrict__ md, const float* __restrict__ kpo,
    const float* __restrict__ be, float* __restrict__ out) {

    __shared__ __attribute__((aligned(16))) unsigned short Bs[2][PT_][BPAD]; // 52224 B
    __shared__ float pwS[2][PT_][C2_];     // [buf][p][d]  8192 B
    __shared__ float mdS[PT_][3];          // 384 B
    __shared__ float kpoS[C2_ * K_ * 3];   // 4992 B
    __shared__ float biasS[DR_];           // 1536 B

    const int tid  = threadIdx.x;
    const int bid  = blockIdx.x;
    const int b    = bid >> 8;
    const int p0   = (bid & 255) << 5;
    const int lane = tid & 63;
    const int wid  = tid >> 6;
    const int rowm = lane & 15;
    const int quad = lane >> 4;

    // this thread's fm-slice decomposition (12 float4 per thread, coalesced)
    float4 pf[12];
    int pf_c[12], pf_jj[12];
    #pragma unroll
    for (int j = 0; j < 12; j++) {
        int f = j * 256 + tid;
        pf_c[j]  = f / 96;
        pf_jj[j] = f - pf_c[j] * 96;
    }

    #define LOAD_PF(kk)                                                                  \
        { _Pragma("unroll")                                                              \
          for (int j = 0; j < 12; j++) {                                                 \
            const float4* src = (const float4*)(fm +                                     \
                ((((size_t)b * C1_ + pf_c[j]) * K_ + (kk)) * P_ + p0) * A_) + pf_jj[j];  \
            pf[j] = *src;                                                                \
          } }

    #define STORE_PF(bufw)                                                               \
        { _Pragma("unroll")                                                              \
          for (int j = 0; j < 12; j++) {                                                 \
            int pl = pf_jj[j] / 3, aseg = (pf_jj[j] - pl * 3) * 4;                       \
            ushort4 pk = make_ushort4(f2bf(pf[j].x), f2bf(pf[j].y),                      \
                                      f2bf(pf[j].z), f2bf(pf[j].w));                     \
            *(ushort4*)&Bs[bufw][pl][pf_c[j] * A_ + aseg] = pk;                          \
          } }

    #define CALC_PW(bufw, kk)                                                            \
        { for (int i = tid; i < C2_ * PT_; i += 256) {                                   \
            int d = i >> 5, pl = i & 31;                                                 \
            const float* kv = &kpoS[(d * K_ + (kk)) * 3];                                \
            float s = mdS[pl][0] * kv[0] + mdS[pl][1] * kv[1] + mdS[pl][2] * kv[2];      \
            pwS[bufw][pl][d] = fmaxf(s, 0.f);                                            \
          } }

    // A-fragment loads, straight from global (L2-hot)
    const unsigned short* awbase = WT + (size_t)(wid * 96 + rowm) * CA_ + quad * 8;
    #define LOAD_A(dst, kk, ch)                                                          \
        { const unsigned short* ap = awbase + (size_t)(kk) * (DR_ * CA_) + (ch) * 32;    \
          _Pragma("unroll")                                                              \
          for (int mt = 0; mt < 6; mt++) dst[mt] = *(const short8*)(ap + mt * 16 * CA_); }

    // small tables
    for (int i = tid; i < PT_ * 3; i += 256) {
        int p = i / 3, c = i % 3;
        mdS[p][c] = md[((size_t)b * P_ + p0 + p) * 3 + c];
    }
    for (int i = tid; i < C2_ * K_ * 3; i += 256) kpoS[i] = kpo[i];
    for (int i = tid; i < DR_; i += 256) biasS[i] = be[i];

    floatx4 acc_o[6][2];
    floatx4 acc_k[6][2];
    #pragma unroll
    for (int mt = 0; mt < 6; mt++)
        #pragma unroll
        for (int nt = 0; nt < 2; nt++) { acc_o[mt][nt] = (floatx4)0.f; acc_k[mt][nt] = (floatx4)0.f; }

    short8 abuf[2][6];

    // ---- prologue ----
    LOAD_PF(0);
    __syncthreads();              // tables visible
    STORE_PF(0);                  // waits pf(0)
    CALC_PW(0, 0);
    LOAD_A(abuf[0], 0, 0);        // chunk 0 of k=0, issued BEFORE the big pf batch
    LOAD_PF(1);

    for (int k = 0; k < K_; k++) {
        const int buf = k & 1;
        __syncthreads();          // publish Bs[buf], pwS[buf]; retire prior readers

        #pragma unroll
        for (int ch = 0; ch < 12; ch++) {
            if (ch < 11) LOAD_A(abuf[(ch + 1) & 1], k, ch + 1);
            short8 bfr[2];
            #pragma unroll
            for (int nt = 0; nt < 2; nt++)
                bfr[nt] = *(const short8*)(&Bs[buf][nt * 16 + rowm][ch * 32 + quad * 8]);
            const short8* af = abuf[ch & 1];
            #pragma unroll
            for (int mt = 0; mt < 6; mt++)
                #pragma unroll
                for (int nt = 0; nt < 2; nt++)
                    acc_k[mt][nt] = __builtin_amdgcn_mfma_f32_16x16x32_bf16(af[mt], bfr[nt], acc_k[mt][nt], 0, 0, 0);
        }

        // epilogue-k: acc_o += pw[p,d] * acc_k
        #pragma unroll
        for (int mt = 0; mt < 6; mt++) {
            int drb = wid * 96 + mt * 16 + quad * 4;
            #pragma unroll
            for (int reg = 0; reg < 4; reg++) {
                int d = (drb + reg) / 12;
                #pragma unroll
                for (int nt = 0; nt < 2; nt++) {
                    float pv = pwS[buf][nt * 16 + rowm][d];
                    acc_o[mt][nt][reg] += pv * acc_k[mt][nt][reg];
                    acc_k[mt][nt][reg] = 0.f;
                }
            }
        }

        // stage k+1 into the other buffer (no barrier: other waves only touch buf)
        if (k + 1 < K_) {
            STORE_PF(buf ^ 1);    // pf(k+1) already drained by A-frag waits
            CALC_PW(buf ^ 1, k + 1);
            LOAD_A(abuf[0], k + 1, 0);   // before pf batch -> chunk-0 wait won't drain HBM loads
        }
        if (k + 2 < K_) LOAD_PF(k + 2);
    }

    // ---- final: relu(acc_o + bias_eff) -> out[b,d,p,r] ----
    #pragma unroll
    for (int mt = 0; mt < 6; mt++) {
        #pragma unroll
        for (int reg = 0; reg < 4; reg++) {
            int dr = wid * 96 + mt * 16 + quad * 4 + reg;
            int d = dr / 12, r = dr - d * 12;
            #pragma unroll
            for (int nt = 0; nt < 2; nt++) {
                int p = p0 + nt * 16 + rowm;
                float v = acc_o[mt][nt][reg] + biasS[dr];
                out[(((size_t)b * C2_ + d) * P_ + p) * A_ + r] = fmaxf(v, 0.f);
            }
        }
    }
}

// ---------------- launcher ----------------
extern "C" void kernel_launch(void* const* d_in, const int* in_sizes, int n_in,
                              void* d_out, int out_size, void* d_ws, size_t ws_size,
                              hipStream_t stream) {
    const int*   nbr     = (const int*)d_in[0];
    const float* verts   = (const float*)d_in[1];
    const float* fm      = (const float*)d_in[2];
    const float* W       = (const float*)d_in[3];
    const float* bias    = (const float*)d_in[4];
    const float* kpw     = (const float*)d_in[5];
    const float* vs      = (const float*)d_in[6];
    const int*   idx_map = (const int*)d_in[7];
    const int*   tivr    = (const int*)d_in[8];
    const int*   tir     = (const int*)d_in[9];
    const int*   lvl     = (const int*)d_in[10];
    float* out = (float*)d_out;

    char* ws = (char*)d_ws;
    unsigned short* WT2 = (unsigned short*)ws;            // 13*384*384*2 = 3,833,856 B
    float* md_ws  = (float*)(ws + 4000000);               // 196,608 B
    float* kpo_ws = (float*)(ws + 4200000);               // 4,992 B
    float* be_ws  = (float*)(ws + 4210000);               // 1,536 B

    {
        const int TOT = K_ * DR_ * CA_;                   // 1,916,928
        build_wt<<<(TOT + 255) / 256, 256, 0, stream>>>(W, kpw, idx_map, tivr, tir, WT2);
    }
    build_md<<<(B_ * P_) / 256, 256, 0, stream>>>(nbr, verts, md_ws);
    build_kpo<<<7, 64, 0, stream>>>(kpw, idx_map, vs, kpo_ws);
    build_be<<<6, 64, 0, stream>>>(bias, lvl, tivr, be_ws);

    main_gemm<<<B_ * (P_ / PT_), 256, 0, stream>>>(fm, WT2, md_ws, kpo_ws, be_ws, out);
}